// Round 1
// baseline (608.159 us; speedup 1.0000x reference)
//
#include <hip/hip_runtime.h>
#include <hip/hip_bf16.h>

typedef __bf16 bf16;
typedef __bf16 bf16x8 __attribute__((ext_vector_type(8)));
typedef float floatx4 __attribute__((ext_vector_type(4)));

#define B_    8
#define N_    4096
#define C_    512
#define BN_   32768      // B_*N_
#define HID_  2048
#define SCALE_ 0.125f    // 64^-0.5

// async 16B global -> LDS (m97 lever)
__device__ __forceinline__ void load_lds16(const void* g, void* l) {
    __builtin_amdgcn_global_load_lds(
        (const __attribute__((address_space(1))) void*)g,
        (__attribute__((address_space(3))) void*)l, 16, 0, 0);
}

// ====================== dtype sniff ========================================
__global__ void sniff_kernel(const unsigned int* __restrict__ xw, int* __restrict__ flag)
{
    int t = threadIdx.x;
    int votes = 0;
#pragma unroll
    for (int i = 0; i < 4; i++) {
        unsigned w = xw[t * 4 + i];
        if (w == 0u) continue;
        unsigned a = w & 0xFFFFu;
        unsigned e = (a >> 7) & 0xFFu;
        if (a != 0u && e >= 110u && e <= 135u) votes++; else votes--;
    }
#pragma unroll
    for (int off = 32; off; off >>= 1) votes += __shfl_xor(votes, off);
    __shared__ int s[4];
    if ((t & 63) == 0) s[t >> 6] = votes;
    __syncthreads();
    if (t == 0) *flag = (s[0] + s[1] + s[2] + s[3]) > 0 ? 1 : 0;  // 1 = bf16
}

// ====================== param conversion ===================================
struct ConvArgs {
    const void* src[12];
    unsigned    dstoff[12];
    int         n[12];
};

__global__ __launch_bounds__(256) void convert_params(
    ConvArgs args, char* __restrict__ ws, const int* __restrict__ flag)
{
    int seg = blockIdx.y;
    int n = args.n[seg];
    int base = blockIdx.x * 2048;
    if (base >= n) return;
    bf16* dst = (bf16*)(ws + args.dstoff[seg]);
    const void* src = args.src[seg];
    bool isbf = (*flag != 0);
#pragma unroll
    for (int j = 0; j < 8; j++) {
        int idx = base + threadIdx.x + j * 256;
        if (idx < n) {
            float v = isbf ? (float)((const bf16*)src)[idx]
                           : ((const float*)src)[idx];
            dst[idx] = (bf16)v;
        }
    }
}

// ====================== LayerNorm variants =================================
__device__ __forceinline__ void ln_core(float f[8], const bf16* w, const bf16* b,
                                        int lane, bf16* outp)
{
    float s = 0.f, sq = 0.f;
#pragma unroll
    for (int j = 0; j < 8; j++) { s += f[j]; sq += f[j]*f[j]; }
#pragma unroll
    for (int off = 32; off; off >>= 1) { s += __shfl_xor(s, off); sq += __shfl_xor(sq, off); }
    float mean = s * (1.f/512.f);
    float var  = sq * (1.f/512.f) - mean*mean;
    float inv  = rsqrtf(var + 1e-5f);
    bf16x8 wv = *(const bf16x8*)(w + lane*8);
    bf16x8 bv = *(const bf16x8*)(b + lane*8);
    bf16x8 o;
#pragma unroll
    for (int j = 0; j < 8; j++) o[j] = (bf16)((f[j]-mean)*inv*(float)wv[j] + (float)bv[j]);
    *(bf16x8*)outp = o;
}

__global__ __launch_bounds__(256) void ln_dyn_kernel(
    const void* __restrict__ xv, const bf16* __restrict__ w,
    const bf16* __restrict__ b, bf16* __restrict__ out, const int* __restrict__ flag)
{
    int wave = threadIdx.x >> 6, lane = threadIdx.x & 63;
    size_t row = (size_t)blockIdx.x * 4 + wave;
    float f[8];
    if (*flag) {
        bf16x8 v = *(const bf16x8*)((const bf16*)xv + row * C_ + lane * 8);
#pragma unroll
        for (int j = 0; j < 8; j++) f[j] = (float)v[j];
    } else {
        const float4* p = (const float4*)((const float*)xv + row * C_ + lane * 8);
        float4 v0 = p[0], v1 = p[1];
        f[0]=v0.x; f[1]=v0.y; f[2]=v0.z; f[3]=v0.w;
        f[4]=v1.x; f[5]=v1.y; f[6]=v1.z; f[7]=v1.w;
    }
    ln_core(f, w, b, lane, out + row * C_ + lane*8);
}

__global__ __launch_bounds__(256) void ln_b16_kernel(
    const bf16* __restrict__ x, const bf16* __restrict__ w,
    const bf16* __restrict__ b, bf16* __restrict__ out)
{
    int wave = threadIdx.x >> 6, lane = threadIdx.x & 63;
    size_t row = (size_t)blockIdx.x * 4 + wave;
    bf16x8 v = *(const bf16x8*)(x + row * C_ + lane * 8);
    float f[8];
#pragma unroll
    for (int j = 0; j < 8; j++) f[j] = (float)v[j];
    ln_core(f, w, b, lane, out + row * C_ + lane*8);
}

__global__ __launch_bounds__(256) void ln_f32_kernel(
    const float* __restrict__ x, const bf16* __restrict__ w,
    const bf16* __restrict__ b, bf16* __restrict__ out)
{
    int wave = threadIdx.x >> 6, lane = threadIdx.x & 63;
    size_t row = (size_t)blockIdx.x * 4 + wave;
    const float4* p = (const float4*)(x + row * C_ + lane * 8);
    float4 v0 = p[0], v1 = p[1];
    float f[8] = { v0.x, v0.y, v0.z, v0.w, v1.x, v1.y, v1.z, v1.w };
    ln_core(f, w, b, lane, out + row * C_ + lane*8);
}

// ====================== 256x256 8-phase MFMA GEMM ==========================
// T2+T3+T4+T5 template (m201 structure, plain HIP):
//   - 512 threads = 8 waves (2M x 4N), per-wave output 128x64
//   - BK=64 K-tiles; LDS holds 2 K-tiles per operand (8 half-tile slots,
//     128 KiB total); rolling half-tile overwrite schedule
//   - st_16x32 XOR swizzle: pre-swizzled global_load_lds SOURCE + swizzled
//     ds_read address (same involution both sides, rule #21)
//   - raw s_barrier + counted s_waitcnt vmcnt(4) once per K-tile (never 0
//     in steady state); setprio(1) around each 16-MFMA quadrant cluster
// Half-tile release proof: quadrant q of K-tile t reads A-half(q>>1) and
// B-half(q&1).  A0(t) last read q1, B0(t) q2, A1(t)/B1(t) q3.  Stage map:
//   q0 -> A1(t+1), q1 -> B1(t+1), q2 -> A0(t+2), q3 -> B0(t+2)
// (each stage lands exactly one phase after its slot's last read).  The
// vmcnt(4) at q3 allows only {A0(t+2),B0(t+2)} in flight -> everything
// through B1(t+1) landed -> all of K-tile t+1 is resident before phase 4t+4.
enum { EPI_NONE = 0, EPI_BIAS = 1, EPI_BIAS_RESID = 2, EPI_BIAS_GELU = 3, EPI_QKV = 4 };

__device__ __forceinline__ void stage_half(
    const bf16* __restrict__ G, int ldk, bf16* lbase, int t)
{
#pragma unroll
    for (int i = 0; i < 2; i++) {
        int c  = i * 512 + t;                      // 16B chunk index in half-tile
        int cp = c ^ (((c >> 5) & 1) << 1);        // inverse st_16x32 on source
        load_lds16(G + (size_t)(cp >> 3) * ldk + (cp & 7) * 8, lbase + c * 8);
    }
}

#define PHASE(qq)  {                                                           \
    constexpr int aH = (qq) >> 1, bH = (qq) & 1;                               \
    const bf16* Ab = &Asl[s][aH][0][0];                                        \
    const bf16* Bb = &Bsl[s][bH][0][0];                                        \
    bf16x8 af[4][2], bfv[2][2];                                                \
    _Pragma("unroll") for (int mi = 0; mi < 4; mi++) {                         \
        int row = wm * 64 + mi * 16 + l16;                                     \
        int xo  = ((row >> 2) & 1) << 4;                                       \
        _Pragma("unroll") for (int ks = 0; ks < 2; ks++)                       \
            af[mi][ks] = *(const bf16x8*)(Ab + row * 64 +                      \
                          ((ks * 32 + quad * 8) ^ xo));                        \
    }                                                                          \
    _Pragma("unroll") for (int ni = 0; ni < 2; ni++) {                         \
        int row = wn * 32 + ni * 16 + l16;                                     \
        int xo  = ((row >> 2) & 1) << 4;                                       \
        _Pragma("unroll") for (int ks = 0; ks < 2; ks++)                       \
            bfv[ni][ks] = *(const bf16x8*)(Bb + row * 64 +                     \
                          ((ks * 32 + quad * 8) ^ xo));                        \
    }                                                                          \
    if ((qq) == 0 && kt + 1 < NKT)                                             \
        stage_half(A + (size_t)(m0 + 128) * K + (size_t)(kt + 1) * 64, K,      \
                   &Asl[s ^ 1][1][0][0], t);                                   \
    if ((qq) == 1 && kt + 1 < NKT)                                             \
        stage_half(W + (size_t)(n0 + 128) * K + (size_t)(kt + 1) * 64, K,      \
                   &Bsl[s ^ 1][1][0][0], t);                                   \
    if ((qq) == 2 && kt + 2 < NKT)                                             \
        stage_half(A + (size_t)m0 * K + (size_t)(kt + 2) * 64, K,              \
                   &Asl[s][0][0][0], t);                                       \
    if ((qq) == 3 && kt + 2 < NKT)                                             \
        stage_half(W + (size_t)n0 * K + (size_t)(kt + 2) * 64, K,              \
                   &Bsl[s][0][0][0], t);                                       \
    if ((qq) == 3 && kt + 1 < NKT) {                                           \
        if (kt + 2 < NKT) asm volatile("s_waitcnt vmcnt(4)");                  \
        else              asm volatile("s_waitcnt vmcnt(0)");                  \
    }                                                                          \
    __builtin_amdgcn_s_barrier();                                              \
    asm volatile("s_waitcnt lgkmcnt(0)");                                      \
    __builtin_amdgcn_s_setprio(1);                                             \
    _Pragma("unroll") for (int mi = 0; mi < 4; mi++)                           \
    _Pragma("unroll") for (int ni = 0; ni < 2; ni++)                           \
    _Pragma("unroll") for (int ks = 0; ks < 2; ks++)                           \
        acc[aH * 4 + mi][bH * 2 + ni] = __builtin_amdgcn_mfma_f32_16x16x32_bf16( \
            af[mi][ks], bfv[ni][ks], acc[aH * 4 + mi][bH * 2 + ni], 0, 0, 0);  \
    __builtin_amdgcn_s_setprio(0);                                             \
    __builtin_amdgcn_s_barrier();                                              \
}

template<typename OutT, int EPI>
__global__ __launch_bounds__(512, 2) void gemm256(
    const bf16* __restrict__ A, const bf16* __restrict__ W,
    const bf16* __restrict__ bias, const void* __restrict__ resid,
    const int* __restrict__ flag,
    OutT* __restrict__ Cout, bf16* __restrict__ Cout2, int M, int Nn, int K)
{
    __shared__ bf16 Asl[2][2][128][64];   // [slot][half][row][k]  64 KiB
    __shared__ bf16 Bsl[2][2][128][64];   // 64 KiB
    const int t = threadIdx.x;
    const int wv = t >> 6, lane = t & 63;
    const int quad = lane >> 4, l16 = lane & 15;
    const int wm = wv >> 2, wn = wv & 3;          // wave tile: 128 rows x 64 cols
    const int Nt = Nn >> 8;
    const int id = blockIdx.x;
    const int xcd = id & 7, j = id >> 3;
    const int m0 = ((j / Nt) * 8 + xcd) * 256;
    const int n0 = (j % Nt) * 256;
    const int NKT = K >> 6;                        // BK=64 K-tiles

    floatx4 acc[8][4] = {};

    // ---- prologue: K-tile 0 fully + first halves of K-tile 1 ----
    stage_half(A + (size_t)m0 * K,           K, &Asl[0][0][0][0], t);  // A0(0)
    stage_half(W + (size_t)n0 * K,           K, &Bsl[0][0][0][0], t);  // B0(0)
    stage_half(A + (size_t)(m0 + 128) * K,   K, &Asl[0][1][0][0], t);  // A1(0)
    stage_half(W + (size_t)(n0 + 128) * K,   K, &Bsl[0][1][0][0], t);  // B1(0)
    stage_half(A + (size_t)m0 * K + 64,      K, &Asl[1][0][0][0], t);  // A0(1)
    stage_half(W + (size_t)n0 * K + 64,      K, &Bsl[1][0][0][0], t);  // B0(1)
    asm volatile("s_waitcnt vmcnt(4)");    // K-tile 0 landed; A0(1),B0(1) in flight
    __builtin_amdgcn_s_barrier();

    for (int kt = 0; kt < NKT; ++kt) {
        const int s = kt & 1;
        PHASE(0) PHASE(1) PHASE(2) PHASE(3)
    }

    // ---- epilogue ----
    size_t ldc = (size_t)Nn; int csub = 0; bool to2 = false;
    if (EPI == EPI_QKV) {
        if (n0 >= 512) { to2 = true; ldc = 1024; csub = 512; }
        else           { ldc = 512; }
    }
    bool isbf = false;
    if (EPI == EPI_BIAS_RESID) isbf = (*flag != 0);

#pragma unroll
    for (int mg = 0; mg < 8; mg++) {
        int rowg = m0 + (mg >> 2) * 128 + wm * 64 + (mg & 3) * 16 + quad * 4;
#pragma unroll
        for (int ng = 0; ng < 4; ng++) {
            int col = n0 + (ng >> 1) * 128 + wn * 32 + (ng & 1) * 16 + l16;
            float bv = (EPI == EPI_BIAS || EPI == EPI_BIAS_RESID || EPI == EPI_BIAS_GELU)
                       ? (float)bias[col] : 0.f;
#pragma unroll
            for (int r = 0; r < 4; r++) {
                size_t idx = (size_t)(rowg + r) * ldc + (col - csub);
                float v = acc[mg][ng][r] + bv;
                if (EPI == EPI_BIAS_RESID) {
                    float rres = isbf ? (float)((const bf16*)resid)[idx]
                                      : ((const float*)resid)[idx];
                    v += rres;
                }
                if (EPI == EPI_BIAS_GELU)  v = 0.5f * v * (1.f + erff(v * 0.70710678118654752f));
                if (EPI == EPI_QKV && to2) Cout2[idx] = (bf16)v;
                else                       Cout[idx]  = (OutT)v;
            }
        }
    }
}

// ====================== attention (MFMA) ===================================
// grid (8 slices, 64 bh): partial[(bh*8+s)*4096 + d*64+e] over 512 tokens
__global__ __launch_bounds__(256) void attn_logits_mfma(
    const bf16* __restrict__ kv, float* __restrict__ partial)
{
    __shared__ bf16 Kt[64][136];
    __shared__ bf16 Vt[64][136];
    int s = blockIdx.x, bh = blockIdx.y, b = bh >> 3, h = bh & 7;
    int t = threadIdx.x, wave = t >> 6, lane = t & 63;
    int quad = lane >> 4, l16 = lane & 15;
    floatx4 acc[4] = {};
    for (int c = 0; c < 4; c++) {
        int n0 = s * 512 + c * 128;
        {
            int isv = t >> 7;
            int r   = t & 127;
            const bf16* gp = &kv[((size_t)b * N_ + n0 + r) * 1024 + h * 64 + isv * 512];
            bf16x8 rowv[8];
#pragma unroll
            for (int u = 0; u < 8; u++) rowv[u] = *(const bf16x8*)(gp + u * 8);
            bf16 (*dst)[136] = isv ? Vt : Kt;
#pragma unroll
            for (int u = 0; u < 8; u++)
#pragma unroll
                for (int jj = 0; jj < 8; jj++)
                    dst[u * 8 + jj][r] = rowv[u][jj];
        }
        __syncthreads();
#pragma unroll
        for (int ks = 0; ks < 4; ks++) {
            bf16x8 af = *(const bf16x8*)&Kt[wave * 16 + l16][ks * 32 + quad * 8];
#pragma unroll
            for (int ni = 0; ni < 4; ni++) {
                bf16x8 bfv = *(const bf16x8*)&Vt[ni * 16 + l16][ks * 32 + quad * 8];
                acc[ni] = __builtin_amdgcn_mfma_f32_16x16x32_bf16(af, bfv, acc[ni], 0, 0, 0);
            }
        }
        __syncthreads();
    }
    float* p = partial + ((size_t)bh * 8 + s) * 4096;
#pragma unroll
    for (int ni = 0; ni < 4; ni++)
#pragma unroll
        for (int r = 0; r < 4; r++)
            p[(wave * 16 + quad * 4 + r) * 64 + ni * 16 + l16] = acc[ni][r];
}

// softmax: grid (4, 64); block handles 16 d rows (wave*4 + r)
__global__ __launch_bounds__(256) void attn_softmax_kernel(
    const float* __restrict__ partial, bf16* __restrict__ attnb)
{
    int bh = blockIdx.y;
    int wave = threadIdx.x >> 6, lane = threadIdx.x & 63;
    for (int r = 0; r < 4; r++) {
        int d = blockIdx.x * 16 + wave * 4 + r;
        float v = 0.f;
#pragma unroll
        for (int s = 0; s < 8; s++) v += partial[((size_t)bh*8 + s)*4096 + d*64 + lane];
        v *= SCALE_;
        float m = v;
#pragma unroll
        for (int off = 32; off; off >>= 1) m = fmaxf(m, __shfl_xor(m, off));
        float p = expf(v - m);
        float sum = p;
#pragma unroll
        for (int off = 32; off; off >>= 1) sum += __shfl_xor(sum, off);
        attnb[(size_t)bh*4096 + d*64 + lane] = (bf16)(p / sum);
    }
}

// apply: outT[n][h*64+d] = sum_e attn[d][e] * q[n][h*64+e]
__global__ __launch_bounds__(256) void attn_apply_mfma(
    const bf16* __restrict__ q, const bf16* __restrict__ attnb,
    bf16* __restrict__ outT)
{
    int bh = blockIdx.y, b = bh >> 3, h = bh & 7;
    int t = threadIdx.x, wave = t >> 6, lane = t & 63;
    int quad = lane >> 4, l16 = lane & 15;
    int nbase = blockIdx.x * 256 + wave * 64;
    bf16x8 bfrag[4][2];
#pragma unroll
    for (int di = 0; di < 4; di++)
#pragma unroll
        for (int ks = 0; ks < 2; ks++)
            bfrag[di][ks] = *(const bf16x8*)&attnb[(size_t)bh*4096 + (di*16 + l16)*64 + ks*32 + quad*8];
    floatx4 acc[4][4] = {};
#pragma unroll
    for (int mi = 0; mi < 4; mi++) {
#pragma unroll
        for (int ks = 0; ks < 2; ks++) {
            bf16x8 af = *(const bf16x8*)&q[((size_t)b*N_ + nbase + mi*16 + l16)*512 + h*64 + ks*32 + quad*8];
#pragma unroll
            for (int di = 0; di < 4; di++)
                acc[mi][di] = __builtin_amdgcn_mfma_f32_16x16x32_bf16(af, bfrag[di][ks], acc[mi][di], 0, 0, 0);
        }
    }
#pragma unroll
    for (int mi = 0; mi < 4; mi++)
#pragma unroll
        for (int di = 0; di < 4; di++)
#pragma unroll
            for (int r = 0; r < 4; r++)
                outT[((size_t)b*N_ + nbase + mi*16 + quad*4 + r)*512 + h*64 + di*16 + l16] =
                    (bf16)acc[mi][di][r];
}

// ====================== ECA ================================================
__global__ __launch_bounds__(256) void pooled_kernel(
    const bf16* __restrict__ y, float* __restrict__ pooled)
{
    int bc = blockIdx.x;
    const bf16* p = y + (size_t)bc * 4096 + threadIdx.x * 16;
    float s = 0.f;
#pragma unroll
    for (int i = 0; i < 2; i++) {
        bf16x8 v = *(const bf16x8*)(p + i*8);
#pragma unroll
        for (int j = 0; j < 8; j++) s += (float)v[j];
    }
#pragma unroll
    for (int off = 32; off; off >>= 1) s += __shfl_xor(s, off);
    __shared__ float red[4];
    if ((threadIdx.x & 63) == 0) red[threadIdx.x >> 6] = s;
    __syncthreads();
    if (threadIdx.x == 0)
        pooled[bc] = (red[0] + red[1] + red[2] + red[3]) * (1.f/4096.f);
}

__global__ void gate_kernel(const float* __restrict__ pooled,
                            const bf16* __restrict__ eca_w, float* __restrict__ gate1)
{
    int c = threadIdx.x, b = blockIdx.x;
    float w0 = (float)eca_w[0], w1 = (float)eca_w[1], w2 = (float)eca_w[2];
    const float* p = pooled + b * 512;
    float conv = w1 * p[c];
    if (c > 0)   conv += w0 * p[c-1];
    if (c < 511) conv += w2 * p[c+1];
    float g = 1.f / (1.f + expf(-conv));
    gate1[b * 512 + c] = 1.f + g;
}

// ------- final, layout B: RMW fp32 d_out -------
__global__ __launch_bounds__(256) void final_rmw(
    const bf16* __restrict__ y, const float* __restrict__ gate1,
    float* __restrict__ out)
{
    int b = blockIdx.z, c0 = blockIdx.y * 64, n0 = blockIdx.x * 64;
    __shared__ float ytile[64][65];
    int t = threadIdx.x;
#pragma unroll
    for (int i = 0; i < 2; i++) {
        int chunk = t * 2 + i;
        int ci = chunk >> 3, nj = (chunk & 7) * 8;
        bf16x8 v = *(const bf16x8*)&y[(size_t)b * ((size_t)N_*C_) + (size_t)(c0+ci) * 4096 + n0 + nj];
#pragma unroll
        for (int j = 0; j < 8; j++) ytile[ci][nj+j] = (float)v[j];
    }
    __syncthreads();
    int cc = t & 63, nb = t >> 6;
    float g = gate1[b * 512 + c0 + cc];
    for (int p = 0; p < 16; p++) {
        int nr = p * 4 + nb;
        size_t idx = ((size_t)b * N_ + n0 + nr) * C_ + c0 + cc;
        out[idx] = out[idx] + g * ytile[cc][nr];
    }
}

// ------- final, layout A: read bf16 x2, write fresh fp32 -------
__global__ __launch_bounds__(256) void final_fresh(
    const bf16* __restrict__ y, const bf16* __restrict__ x2b,
    const float* __restrict__ gate1, float* __restrict__ out)
{
    int b = blockIdx.z, c0 = blockIdx.y * 64, n0 = blockIdx.x * 64;
    __shared__ float ytile[64][65];
    int t = threadIdx.x;
#pragma unroll
    for (int i = 0; i < 2; i++) {
        int chunk = t * 2 + i;
        int ci = chunk >> 3, nj = (chunk & 7) * 8;
        bf16x8 v = *(const bf16x8*)&y[(size_t)b * ((size_t)N_*C_) + (size_t)(c0+ci) * 4096 + n0 + nj];
#pragma unroll
        for (int j = 0; j < 8; j++) ytile[ci][nj+j] = (float)v[j];
    }
    __syncthreads();
    int cc = t & 63, nb = t >> 6;
    float g = gate1[b * 512 + c0 + cc];
    for (int p = 0; p < 16; p++) {
        int nr = p * 4 + nb;
        size_t idx = ((size_t)b * N_ + n0 + nr) * C_ + c0 + cc;
        out[idx] = (float)x2b[idx] + g * ytile[cc][nr];
    }
}

// ====================== launcher ===========================================
// Common (both layouts):
//   0: flag | 4K: pooled | 20K: gate1 | 64K-84K: small params bf16
//   1M: qkv_w | 2.5M: proj_w | 3M: fc1_w | 5M: fc2_w
//   7M-15M: partial fp32 (8 slices) | 15M-15.5M: attnb bf16
//   16M-48M: T1 | 48M: kvbuf (64MB)
// Layout A (ws >= 212MB): hbuf 48-176M (full h), x2b bf16 176-210M,
//   proj->x2b, ln_b16, unchunked FC, final_fresh.
// Layout B: hbuf=kvbuf 48-112M, x2 fp32 in d_out, chunked FC, final_rmw.
extern "C" void kernel_launch(void* const* d_in, const int* in_sizes, int n_in,
                              void* d_out, int out_size, void* d_ws, size_t ws_size,
                              hipStream_t stream)
{
    float* outf = (float*)d_out;
    bf16*  outb = (bf16*)d_out;
    char* ws = (char*)d_ws;

    int*   flag    = (int*)ws;
    float* pooled  = (float*)(ws + 4096);
    float* gate1   = (float*)(ws + 20480);
    bf16* ln1_w = (bf16*)(ws + 65536);
    bf16* ln1_b = (bf16*)(ws + 67584);
    bf16* ln2_w = (bf16*)(ws + 69632);
    bf16* ln2_b = (bf16*)(ws + 71680);
    bf16* proj_b= (bf16*)(ws + 73728);
    bf16* fc2_b = (bf16*)(ws + 75776);
    bf16* eca_w = (bf16*)(ws + 77824);
    bf16* fc1_b = (bf16*)(ws + 81920);
    bf16* qkv_w = (bf16*)(ws + ((size_t)1 << 20));
    bf16* proj_w= (bf16*)(ws + (size_t)2621440);
    bf16* fc1_w = (bf16*)(ws + ((size_t)3 << 20));
    bf16* fc2_w = (bf16*)(ws + ((size_t)5 << 20));
    float* partial = (float*)(ws + ((size_t)7  << 20));
    bf16*  attnb   = (bf16*)(ws + ((size_t)15 << 20));
    bf16*  T1      = (bf16*)(ws + ((size_t)16 << 20));
    bf16*  kvbuf   = (bf16*)(ws + ((size_t)48 << 20));
    bf16*  hbuf    = kvbuf;
    bf16*  x2b     = (bf16*)(ws + ((size_t)176 << 20));

    const bool fat = ws_size >= ((size_t)212 << 20);

    // 0. sniff input dtype
    sniff_kernel<<<1, 256, 0, stream>>>((const unsigned int*)d_in[0], flag);

    // 1. convert params to bf16
    ConvArgs ca;
    const int   srcidx[12] = { 1, 2, 6, 7, 5, 11, 12, 9, 3, 4, 8, 10 };
    const unsigned offs[12] = { 65536, 67584, 69632, 71680, 73728, 75776, 77824, 81920,
                                1u<<20, 2621440u, 3u<<20, 5u<<20 };
    for (int i = 0; i < 12; i++) {
        ca.src[i] = d_in[srcidx[i]];
        ca.dstoff[i] = offs[i];
        ca.n[i] = in_sizes[srcidx[i]];
    }
    convert_params<<<dim3(512, 12), 256, 0, stream>>>(ca, ws, flag);

    // 2. LN1 -> T1
    ln_dyn_kernel<<<BN_/4, 256, 0, stream>>>(d_in[0], ln1_w, ln1_b, T1, flag);

    // 3. QKV GEMM: q (bf16) -> d_out, kv -> kvbuf   (Mt=128, Nt=6)
    gemm256<bf16, EPI_QKV><<<768, 512, 0, stream>>>(
        T1, qkv_w, nullptr, nullptr, flag, outb, kvbuf, BN_, 1536, 512);

    // 4. attention
    attn_logits_mfma<<<dim3(8, 64), 256, 0, stream>>>(kvbuf, partial);
    attn_softmax_kernel<<<dim3(4, 64), 256, 0, stream>>>(partial, attnb);
    attn_apply_mfma<<<dim3(16, 64), 256, 0, stream>>>(outb, attnb, T1);

    if (fat) {
        // 5. proj + bias + residual(x) -> x2b (bf16)
        gemm256<bf16, EPI_BIAS_RESID><<<256, 512, 0, stream>>>(
            T1, proj_w, proj_b, d_in[0], flag, x2b, nullptr, BN_, 512, 512);
        // 6. LN2: x2b -> T1
        ln_b16_kernel<<<BN_/4, 256, 0, stream>>>(x2b, ln2_w, ln2_b, T1);
        // 7. FC1 full: T1 -> hbuf (128MB)   (Mt=128, Nt=8)
        gemm256<bf16, EPI_BIAS_GELU><<<1024, 512, 0, stream>>>(
            T1, fc1_w, fc1_b, nullptr, flag, hbuf, nullptr, BN_, 2048, 512);
        // 8. FC2 full: hbuf -> T1 (y)       (Mt=128, Nt=2)
        gemm256<bf16, EPI_BIAS><<<256, 512, 0, stream>>>(
            hbuf, fc2_w, fc2_b, nullptr, flag, T1, nullptr, BN_, 512, 2048);
        // 9. ECA
        pooled_kernel<<<4096, 256, 0, stream>>>(T1, pooled);
        gate_kernel<<<8, 512, 0, stream>>>(pooled, eca_w, gate1);
        // 10. final: fp32 out = x2b + gate*y  (no RMW)
        final_fresh<<<dim3(64, 8, 8), 256, 0, stream>>>(T1, x2b, gate1, outf);
    } else {
        // 5. proj + bias + residual(x) -> x2 (fp32) in d_out
        gemm256<float, EPI_BIAS_RESID><<<256, 512, 0, stream>>>(
            T1, proj_w, proj_b, d_in[0], flag, outf, nullptr, BN_, 512, 512);
        // 6. LN2: d_out fp32 -> T1
        ln_f32_kernel<<<BN_/4, 256, 0, stream>>>(outf, ln2_w, ln2_b, T1);
        // 7-8. chunked FC (hbuf 64MB)
        for (int ch = 0; ch < 2; ch++) {
            bf16* Tch = T1 + (size_t)ch * 16384 * 512;
            gemm256<bf16, EPI_BIAS_GELU><<<512, 512, 0, stream>>>(
                Tch, fc1_w, fc1_b, nullptr, flag, hbuf, nullptr, 16384, 2048, 512);
            gemm256<bf16, EPI_BIAS><<<128, 512, 0, stream>>>(
                hbuf, fc2_w, fc2_b, nullptr, flag, Tch, nullptr, 16384, 512, 2048);
        }
        // 9. ECA
        pooled_kernel<<<4096, 256, 0, stream>>>(T1, pooled);
        gate_kernel<<<8, 512, 0, stream>>>(pooled, eca_w, gate1);
        // 10. final RMW on fp32 d_out
        final_rmw<<<dim3(64, 8, 8), 256, 0, stream>>>(T1, gate1, outf);
    }
}

// Round 2
// 549.851 us; speedup vs baseline: 1.1060x; 1.1060x over previous
//
#include <hip/hip_runtime.h>
#include <hip/hip_bf16.h>

typedef __bf16 bf16;
typedef __bf16 bf16x8 __attribute__((ext_vector_type(8)));
typedef float floatx4 __attribute__((ext_vector_type(4)));

#define B_    8
#define N_    4096
#define C_    512
#define BN_   32768      // B_*N_
#define HID_  2048
#define SCALE_ 0.125f    // 64^-0.5

// async 16B global -> LDS (m97 lever)
__device__ __forceinline__ void load_lds16(const void* g, void* l) {
    __builtin_amdgcn_global_load_lds(
        (const __attribute__((address_space(1))) void*)g,
        (__attribute__((address_space(3))) void*)l, 16, 0, 0);
}

// ====================== dtype sniff ========================================
__global__ void sniff_kernel(const unsigned int* __restrict__ xw, int* __restrict__ flag)
{
    int t = threadIdx.x;
    int votes = 0;
#pragma unroll
    for (int i = 0; i < 4; i++) {
        unsigned w = xw[t * 4 + i];
        if (w == 0u) continue;
        unsigned a = w & 0xFFFFu;
        unsigned e = (a >> 7) & 0xFFu;
        if (a != 0u && e >= 110u && e <= 135u) votes++; else votes--;
    }
#pragma unroll
    for (int off = 32; off; off >>= 1) votes += __shfl_xor(votes, off);
    __shared__ int s[4];
    if ((t & 63) == 0) s[t >> 6] = votes;
    __syncthreads();
    if (t == 0) *flag = (s[0] + s[1] + s[2] + s[3]) > 0 ? 1 : 0;  // 1 = bf16
}

// ====================== param conversion ===================================
struct ConvArgs {
    const void* src[12];
    unsigned    dstoff[12];
    int         n[12];
};

__global__ __launch_bounds__(256) void convert_params(
    ConvArgs args, char* __restrict__ ws, const int* __restrict__ flag)
{
    int seg = blockIdx.y;
    int n = args.n[seg];
    int base = blockIdx.x * 2048;
    if (base >= n) return;
    bf16* dst = (bf16*)(ws + args.dstoff[seg]);
    const void* src = args.src[seg];
    bool isbf = (*flag != 0);
#pragma unroll
    for (int j = 0; j < 8; j++) {
        int idx = base + threadIdx.x + j * 256;
        if (idx < n) {
            float v = isbf ? (float)((const bf16*)src)[idx]
                           : ((const float*)src)[idx];
            dst[idx] = (bf16)v;
        }
    }
}

// ====================== LayerNorm variants =================================
__device__ __forceinline__ void ln_core(float f[8], const bf16* w, const bf16* b,
                                        int lane, bf16* outp)
{
    float s = 0.f, sq = 0.f;
#pragma unroll
    for (int j = 0; j < 8; j++) { s += f[j]; sq += f[j]*f[j]; }
#pragma unroll
    for (int off = 32; off; off >>= 1) { s += __shfl_xor(s, off); sq += __shfl_xor(sq, off); }
    float mean = s * (1.f/512.f);
    float var  = sq * (1.f/512.f) - mean*mean;
    float inv  = rsqrtf(var + 1e-5f);
    bf16x8 wv = *(const bf16x8*)(w + lane*8);
    bf16x8 bv = *(const bf16x8*)(b + lane*8);
    bf16x8 o;
#pragma unroll
    for (int j = 0; j < 8; j++) o[j] = (bf16)((f[j]-mean)*inv*(float)wv[j] + (float)bv[j]);
    *(bf16x8*)outp = o;
}

__global__ __launch_bounds__(256) void ln_dyn_kernel(
    const void* __restrict__ xv, const bf16* __restrict__ w,
    const bf16* __restrict__ b, bf16* __restrict__ out, const int* __restrict__ flag)
{
    int wave = threadIdx.x >> 6, lane = threadIdx.x & 63;
    size_t row = (size_t)blockIdx.x * 4 + wave;
    float f[8];
    if (*flag) {
        bf16x8 v = *(const bf16x8*)((const bf16*)xv + row * C_ + lane * 8);
#pragma unroll
        for (int j = 0; j < 8; j++) f[j] = (float)v[j];
    } else {
        const float4* p = (const float4*)((const float*)xv + row * C_ + lane * 8);
        float4 v0 = p[0], v1 = p[1];
        f[0]=v0.x; f[1]=v0.y; f[2]=v0.z; f[3]=v0.w;
        f[4]=v1.x; f[5]=v1.y; f[6]=v1.z; f[7]=v1.w;
    }
    ln_core(f, w, b, lane, out + row * C_ + lane*8);
}

__global__ __launch_bounds__(256) void ln_b16_kernel(
    const bf16* __restrict__ x, const bf16* __restrict__ w,
    const bf16* __restrict__ b, bf16* __restrict__ out)
{
    int wave = threadIdx.x >> 6, lane = threadIdx.x & 63;
    size_t row = (size_t)blockIdx.x * 4 + wave;
    bf16x8 v = *(const bf16x8*)(x + row * C_ + lane * 8);
    float f[8];
#pragma unroll
    for (int j = 0; j < 8; j++) f[j] = (float)v[j];
    ln_core(f, w, b, lane, out + row * C_ + lane*8);
}

__global__ __launch_bounds__(256) void ln_f32_kernel(
    const float* __restrict__ x, const bf16* __restrict__ w,
    const bf16* __restrict__ b, bf16* __restrict__ out)
{
    int wave = threadIdx.x >> 6, lane = threadIdx.x & 63;
    size_t row = (size_t)blockIdx.x * 4 + wave;
    const float4* p = (const float4*)(x + row * C_ + lane * 8);
    float4 v0 = p[0], v1 = p[1];
    float f[8] = { v0.x, v0.y, v0.z, v0.w, v1.x, v1.y, v1.z, v1.w };
    ln_core(f, w, b, lane, out + row * C_ + lane*8);
}

// ====================== 256x256 8-phase MFMA GEMM ==========================
// T2+T3+T4+T5 template. R1 post-mortem fixes:
//  (a) SWIZZLE: 3-bit XOR  byte ^= (row&7)<<4  (G4 formula for 128B rows);
//      the R1 1-bit st_16x32 variant left a 4x slot-aliasing -> 12.6M
//      bank-conflict cycles. Applied as the same involution on the
//      global_load_lds SOURCE column and the ds_read address (rule #21).
//  (b) FRAG REUSE: gray-code phase order (A0B0 -> A0B1 -> A1B1 -> A1B0)
//      keeping both B-half frags live: 24 ds_read_b128 per K-tile per wave
//      (phases load 12/4/8/0) instead of R1's 48 -> LDS off critical path
//      (1536 clk/CU/K-tile vs MFMA floor 2061 clk).
// Slot release/stage proof (read order changed, stage map unchanged):
//   reads: A0(t)@q0, B0(t)@q0 (regs reused @q3), B1(t)@q1, A1(t)@q2.
//   stages: q0->A1(t+1) [slot free after q2(t-1)], q1->B1(t+1) [free q1(t-1)],
//           q2->A0(t+2) [free q0(t)], q3->B0(t+2) [free q0(t)].
//   vmcnt(4)@q3 leaves only {A0(t+2),B0(t+2)} in flight -> K-tile t+1 fully
//   resident before q0(t+1).
enum { EPI_NONE = 0, EPI_BIAS = 1, EPI_BIAS_RESID = 2, EPI_BIAS_GELU = 3, EPI_QKV = 4 };

__device__ __forceinline__ void stage_half(
    const bf16* __restrict__ G, int ldk, bf16* lbase, int t)
{
#pragma unroll
    for (int i = 0; i < 2; i++) {
        int c  = i * 512 + t;          // 16B chunk index: row = c>>3, phys slot = c&7
        int r  = c >> 3;
        int ls = (c & 7) ^ (r & 7);    // logical (global) slot for this phys slot
        load_lds16(G + (size_t)r * ldk + ls * 8, lbase + c * 8);
    }
}

// LDS reads: global (row, col8) lives at  row*64 + (col8 ^ ((row&7)<<3))
#define LOAD_AF(half)                                                          \
    _Pragma("unroll") for (int mi = 0; mi < 4; mi++) {                         \
        int row = wm * 64 + mi * 16 + l16;                                     \
        _Pragma("unroll") for (int ks = 0; ks < 2; ks++)                       \
            af[mi][ks] = *(const bf16x8*)(&Asl[s][half][0][0] + row * 64 +     \
                ((ks * 32 + quad * 8) ^ ((row & 7) << 3)));                    \
    }
#define LOAD_BF(dst, half)                                                     \
    _Pragma("unroll") for (int ni = 0; ni < 2; ni++) {                         \
        int row = wn * 32 + ni * 16 + l16;                                     \
        _Pragma("unroll") for (int ks = 0; ks < 2; ks++)                       \
            dst[ni][ks] = *(const bf16x8*)(&Bsl[s][half][0][0] + row * 64 +    \
                ((ks * 32 + quad * 8) ^ ((row & 7) << 3)));                    \
    }
#define MFMA_Q(AH, BH, BFR)                                                    \
    __builtin_amdgcn_s_barrier();                                              \
    asm volatile("s_waitcnt lgkmcnt(0)");                                      \
    __builtin_amdgcn_s_setprio(1);                                             \
    _Pragma("unroll") for (int mi = 0; mi < 4; mi++)                           \
    _Pragma("unroll") for (int ni = 0; ni < 2; ni++)                           \
    _Pragma("unroll") for (int ks = 0; ks < 2; ks++)                           \
        acc[(AH)*4+mi][(BH)*2+ni] = __builtin_amdgcn_mfma_f32_16x16x32_bf16(   \
            af[mi][ks], BFR[ni][ks], acc[(AH)*4+mi][(BH)*2+ni], 0, 0, 0);      \
    __builtin_amdgcn_s_setprio(0);                                             \
    __builtin_amdgcn_s_barrier();

template<typename OutT, int EPI>
__global__ __launch_bounds__(512, 2) void gemm256(
    const bf16* __restrict__ A, const bf16* __restrict__ W,
    const bf16* __restrict__ bias, const void* __restrict__ resid,
    const int* __restrict__ flag,
    OutT* __restrict__ Cout, bf16* __restrict__ Cout2, int M, int Nn, int K)
{
    __shared__ bf16 Asl[2][2][128][64];   // [slot][half][row][k]  64 KiB
    __shared__ bf16 Bsl[2][2][128][64];   // 64 KiB
    const int t = threadIdx.x;
    const int wv = t >> 6, lane = t & 63;
    const int quad = lane >> 4, l16 = lane & 15;
    const int wm = wv >> 2, wn = wv & 3;          // wave tile: 128 rows x 64 cols
    const int Nt = Nn >> 8;
    const int id = blockIdx.x;
    const int xcd = id & 7, j = id >> 3;
    const int m0 = ((j / Nt) * 8 + xcd) * 256;
    const int n0 = (j % Nt) * 256;
    const int NKT = K >> 6;                        // BK=64 K-tiles

    floatx4 acc[8][4] = {};
    bf16x8 af[4][2], bf0[2][2], bf1[2][2];

    // ---- prologue: K-tile 0 fully + first halves of K-tile 1 ----
    stage_half(A + (size_t)m0 * K,           K, &Asl[0][0][0][0], t);  // A0(0)
    stage_half(W + (size_t)n0 * K,           K, &Bsl[0][0][0][0], t);  // B0(0)
    stage_half(A + (size_t)(m0 + 128) * K,   K, &Asl[0][1][0][0], t);  // A1(0)
    stage_half(W + (size_t)(n0 + 128) * K,   K, &Bsl[0][1][0][0], t);  // B1(0)
    stage_half(A + (size_t)m0 * K + 64,      K, &Asl[1][0][0][0], t);  // A0(1)
    stage_half(W + (size_t)n0 * K + 64,      K, &Bsl[1][0][0][0], t);  // B0(1)
    asm volatile("s_waitcnt vmcnt(4)");    // K-tile 0 landed; A0(1),B0(1) in flight
    __builtin_amdgcn_s_barrier();

    for (int kt = 0; kt < NKT; ++kt) {
        const int s = kt & 1;
        // ---- phase 0: (A0,B0) — 12 ds_reads ----
        LOAD_AF(0)
        LOAD_BF(bf0, 0)
        if (kt + 1 < NKT)
            stage_half(A + (size_t)(m0 + 128) * K + (size_t)(kt + 1) * 64, K,
                       &Asl[s ^ 1][1][0][0], t);
        MFMA_Q(0, 0, bf0)
        // ---- phase 1: (A0,B1) — 4 ds_reads, reuse af ----
        LOAD_BF(bf1, 1)
        if (kt + 1 < NKT)
            stage_half(W + (size_t)(n0 + 128) * K + (size_t)(kt + 1) * 64, K,
                       &Bsl[s ^ 1][1][0][0], t);
        MFMA_Q(0, 1, bf1)
        // ---- phase 2: (A1,B1) — 8 ds_reads, reuse bf1 ----
        LOAD_AF(1)
        if (kt + 2 < NKT)
            stage_half(A + (size_t)m0 * K + (size_t)(kt + 2) * 64, K,
                       &Asl[s][0][0][0], t);
        MFMA_Q(1, 1, bf1)
        // ---- phase 3: (A1,B0) — 0 ds_reads, reuse af & bf0 ----
        if (kt + 2 < NKT)
            stage_half(W + (size_t)n0 * K + (size_t)(kt + 2) * 64, K,
                       &Bsl[s][0][0][0], t);
        if (kt + 1 < NKT) {
            if (kt + 2 < NKT) asm volatile("s_waitcnt vmcnt(4)");
            else              asm volatile("s_waitcnt vmcnt(0)");
        }
        MFMA_Q(1, 0, bf0)
    }

    // ---- epilogue ----
    size_t ldc = (size_t)Nn; int csub = 0; bool to2 = false;
    if (EPI == EPI_QKV) {
        if (n0 >= 512) { to2 = true; ldc = 1024; csub = 512; }
        else           { ldc = 512; }
    }
    bool isbf = false;
    if (EPI == EPI_BIAS_RESID) isbf = (*flag != 0);

#pragma unroll
    for (int mg = 0; mg < 8; mg++) {
        int rowg = m0 + (mg >> 2) * 128 + wm * 64 + (mg & 3) * 16 + quad * 4;
#pragma unroll
        for (int ng = 0; ng < 4; ng++) {
            int col = n0 + (ng >> 1) * 128 + wn * 32 + (ng & 1) * 16 + l16;
            float bv = (EPI == EPI_BIAS || EPI == EPI_BIAS_RESID || EPI == EPI_BIAS_GELU)
                       ? (float)bias[col] : 0.f;
#pragma unroll
            for (int r = 0; r < 4; r++) {
                size_t idx = (size_t)(rowg + r) * ldc + (col - csub);
                float v = acc[mg][ng][r] + bv;
                if (EPI == EPI_BIAS_RESID) {
                    float rres = isbf ? (float)((const bf16*)resid)[idx]
                                      : ((const float*)resid)[idx];
                    v += rres;
                }
                if (EPI == EPI_BIAS_GELU)  v = 0.5f * v * (1.f + erff(v * 0.70710678118654752f));
                if (EPI == EPI_QKV && to2) Cout2[idx] = (bf16)v;
                else                       Cout[idx]  = (OutT)v;
            }
        }
    }
}

// ====================== attention (MFMA) ===================================
// grid (8 slices, 64 bh): partial[(bh*8+s)*4096 + d*64+e] over 512 tokens
__global__ __launch_bounds__(256) void attn_logits_mfma(
    const bf16* __restrict__ kv, float* __restrict__ partial)
{
    __shared__ bf16 Kt[64][136];
    __shared__ bf16 Vt[64][136];
    int s = blockIdx.x, bh = blockIdx.y, b = bh >> 3, h = bh & 7;
    int t = threadIdx.x, wave = t >> 6, lane = t & 63;
    int quad = lane >> 4, l16 = lane & 15;
    floatx4 acc[4] = {};
    for (int c = 0; c < 4; c++) {
        int n0 = s * 512 + c * 128;
        {
            int isv = t >> 7;
            int r   = t & 127;
            const bf16* gp = &kv[((size_t)b * N_ + n0 + r) * 1024 + h * 64 + isv * 512];
            bf16x8 rowv[8];
#pragma unroll
            for (int u = 0; u < 8; u++) rowv[u] = *(const bf16x8*)(gp + u * 8);
            bf16 (*dst)[136] = isv ? Vt : Kt;
#pragma unroll
            for (int u = 0; u < 8; u++)
#pragma unroll
                for (int jj = 0; jj < 8; jj++)
                    dst[u * 8 + jj][r] = rowv[u][jj];
        }
        __syncthreads();
#pragma unroll
        for (int ks = 0; ks < 4; ks++) {
            bf16x8 af = *(const bf16x8*)&Kt[wave * 16 + l16][ks * 32 + quad * 8];
#pragma unroll
            for (int ni = 0; ni < 4; ni++) {
                bf16x8 bfv = *(const bf16x8*)&Vt[ni * 16 + l16][ks * 32 + quad * 8];
                acc[ni] = __builtin_amdgcn_mfma_f32_16x16x32_bf16(af, bfv, acc[ni], 0, 0, 0);
            }
        }
        __syncthreads();
    }
    float* p = partial + ((size_t)bh * 8 + s) * 4096;
#pragma unroll
    for (int ni = 0; ni < 4; ni++)
#pragma unroll
        for (int r = 0; r < 4; r++)
            p[(wave * 16 + quad * 4 + r) * 64 + ni * 16 + l16] = acc[ni][r];
}

// softmax: grid (4, 64); block handles 16 d rows (wave*4 + r)
__global__ __launch_bounds__(256) void attn_softmax_kernel(
    const float* __restrict__ partial, bf16* __restrict__ attnb)
{
    int bh = blockIdx.y;
    int wave = threadIdx.x >> 6, lane = threadIdx.x & 63;
    for (int r = 0; r < 4; r++) {
        int d = blockIdx.x * 16 + wave * 4 + r;
        float v = 0.f;
#pragma unroll
        for (int s = 0; s < 8; s++) v += partial[((size_t)bh*8 + s)*4096 + d*64 + lane];
        v *= SCALE_;
        float m = v;
#pragma unroll
        for (int off = 32; off; off >>= 1) m = fmaxf(m, __shfl_xor(m, off));
        float p = expf(v - m);
        float sum = p;
#pragma unroll
        for (int off = 32; off; off >>= 1) sum += __shfl_xor(sum, off);
        attnb[(size_t)bh*4096 + d*64 + lane] = (bf16)(p / sum);
    }
}

// apply: outT[n][h*64+d] = sum_e attn[d][e] * q[n][h*64+e]
__global__ __launch_bounds__(256) void attn_apply_mfma(
    const bf16* __restrict__ q, const bf16* __restrict__ attnb,
    bf16* __restrict__ outT)
{
    int bh = blockIdx.y, b = bh >> 3, h = bh & 7;
    int t = threadIdx.x, wave = t >> 6, lane = t & 63;
    int quad = lane >> 4, l16 = lane & 15;
    int nbase = blockIdx.x * 256 + wave * 64;
    bf16x8 bfrag[4][2];
#pragma unroll
    for (int di = 0; di < 4; di++)
#pragma unroll
        for (int ks = 0; ks < 2; ks++)
            bfrag[di][ks] = *(const bf16x8*)&attnb[(size_t)bh*4096 + (di*16 + l16)*64 + ks*32 + quad*8];
    floatx4 acc[4][4] = {};
#pragma unroll
    for (int mi = 0; mi < 4; mi++) {
#pragma unroll
        for (int ks = 0; ks < 2; ks++) {
            bf16x8 af = *(const bf16x8*)&q[((size_t)b*N_ + nbase + mi*16 + l16)*512 + h*64 + ks*32 + quad*8];
#pragma unroll
            for (int di = 0; di < 4; di++)
                acc[mi][di] = __builtin_amdgcn_mfma_f32_16x16x32_bf16(af, bfrag[di][ks], acc[mi][di], 0, 0, 0);
        }
    }
#pragma unroll
    for (int mi = 0; mi < 4; mi++)
#pragma unroll
        for (int di = 0; di < 4; di++)
#pragma unroll
            for (int r = 0; r < 4; r++)
                outT[((size_t)b*N_ + nbase + mi*16 + quad*4 + r)*512 + h*64 + di*16 + l16] =
                    (bf16)acc[mi][di][r];
}

// ====================== ECA ================================================
__global__ __launch_bounds__(256) void pooled_kernel(
    const bf16* __restrict__ y, float* __restrict__ pooled)
{
    int bc = blockIdx.x;
    const bf16* p = y + (size_t)bc * 4096 + threadIdx.x * 16;
    float s = 0.f;
#pragma unroll
    for (int i = 0; i < 2; i++) {
        bf16x8 v = *(const bf16x8*)(p + i*8);
#pragma unroll
        for (int j = 0; j < 8; j++) s += (float)v[j];
    }
#pragma unroll
    for (int off = 32; off; off >>= 1) s += __shfl_xor(s, off);
    __shared__ float red[4];
    if ((threadIdx.x & 63) == 0) red[threadIdx.x >> 6] = s;
    __syncthreads();
    if (threadIdx.x == 0)
        pooled[bc] = (red[0] + red[1] + red[2] + red[3]) * (1.f/4096.f);
}

__global__ void gate_kernel(const float* __restrict__ pooled,
                            const bf16* __restrict__ eca_w, float* __restrict__ gate1)
{
    int c = threadIdx.x, b = blockIdx.x;
    float w0 = (float)eca_w[0], w1 = (float)eca_w[1], w2 = (float)eca_w[2];
    const float* p = pooled + b * 512;
    float conv = w1 * p[c];
    if (c > 0)   conv += w0 * p[c-1];
    if (c < 511) conv += w2 * p[c+1];
    float g = 1.f / (1.f + expf(-conv));
    gate1[b * 512 + c] = 1.f + g;
}

// ------- final, layout B: RMW fp32 d_out -------
__global__ __launch_bounds__(256) void final_rmw(
    const bf16* __restrict__ y, const float* __restrict__ gate1,
    float* __restrict__ out)
{
    int b = blockIdx.z, c0 = blockIdx.y * 64, n0 = blockIdx.x * 64;
    __shared__ float ytile[64][65];
    int t = threadIdx.x;
#pragma unroll
    for (int i = 0; i < 2; i++) {
        int chunk = t * 2 + i;
        int ci = chunk >> 3, nj = (chunk & 7) * 8;
        bf16x8 v = *(const bf16x8*)&y[(size_t)b * ((size_t)N_*C_) + (size_t)(c0+ci) * 4096 + n0 + nj];
#pragma unroll
        for (int j = 0; j < 8; j++) ytile[ci][nj+j] = (float)v[j];
    }
    __syncthreads();
    int cc = t & 63, nb = t >> 6;
    float g = gate1[b * 512 + c0 + cc];
    for (int p = 0; p < 16; p++) {
        int nr = p * 4 + nb;
        size_t idx = ((size_t)b * N_ + n0 + nr) * C_ + c0 + cc;
        out[idx] = out[idx] + g * ytile[cc][nr];
    }
}

// ------- final, layout A: read bf16 x2, write fresh fp32 -------
__global__ __launch_bounds__(256) void final_fresh(
    const bf16* __restrict__ y, const bf16* __restrict__ x2b,
    const float* __restrict__ gate1, float* __restrict__ out)
{
    int b = blockIdx.z, c0 = blockIdx.y * 64, n0 = blockIdx.x * 64;
    __shared__ float ytile[64][65];
    int t = threadIdx.x;
#pragma unroll
    for (int i = 0; i < 2; i++) {
        int chunk = t * 2 + i;
        int ci = chunk >> 3, nj = (chunk & 7) * 8;
        bf16x8 v = *(const bf16x8*)&y[(size_t)b * ((size_t)N_*C_) + (size_t)(c0+ci) * 4096 + n0 + nj];
#pragma unroll
        for (int j = 0; j < 8; j++) ytile[ci][nj+j] = (float)v[j];
    }
    __syncthreads();
    int cc = t & 63, nb = t >> 6;
    float g = gate1[b * 512 + c0 + cc];
    for (int p = 0; p < 16; p++) {
        int nr = p * 4 + nb;
        size_t idx = ((size_t)b * N_ + n0 + nr) * C_ + c0 + cc;
        out[idx] = (float)x2b[idx] + g * ytile[cc][nr];
    }
}

// ====================== launcher ===========================================
// Common (both layouts):
//   0: flag | 4K: pooled | 20K: gate1 | 64K-84K: small params bf16
//   1M: qkv_w | 2.5M: proj_w | 3M: fc1_w | 5M: fc2_w
//   7M-15M: partial fp32 (8 slices) | 15M-15.5M: attnb bf16
//   16M-48M: T1 | 48M: kvbuf (64MB)
// Layout A (ws >= 212MB): hbuf 48-176M (full h), x2b bf16 176-210M,
//   proj->x2b, ln_b16, unchunked FC, final_fresh.
// Layout B: hbuf=kvbuf 48-112M, x2 fp32 in d_out, chunked FC, final_rmw.
extern "C" void kernel_launch(void* const* d_in, const int* in_sizes, int n_in,
                              void* d_out, int out_size, void* d_ws, size_t ws_size,
                              hipStream_t stream)
{
    float* outf = (float*)d_out;
    bf16*  outb = (bf16*)d_out;
    char* ws = (char*)d_ws;

    int*   flag    = (int*)ws;
    float* pooled  = (float*)(ws + 4096);
    float* gate1   = (float*)(ws + 20480);
    bf16* ln1_w = (bf16*)(ws + 65536);
    bf16* ln1_b = (bf16*)(ws + 67584);
    bf16* ln2_w = (bf16*)(ws + 69632);
    bf16* ln2_b = (bf16*)(ws + 71680);
    bf16* proj_b= (bf16*)(ws + 73728);
    bf16* fc2_b = (bf16*)(ws + 75776);
    bf16* eca_w = (bf16*)(ws + 77824);
    bf16* fc1_b = (bf16*)(ws + 81920);
    bf16* qkv_w = (bf16*)(ws + ((size_t)1 << 20));
    bf16* proj_w= (bf16*)(ws + (size_t)2621440);
    bf16* fc1_w = (bf16*)(ws + ((size_t)3 << 20));
    bf16* fc2_w = (bf16*)(ws + ((size_t)5 << 20));
    float* partial = (float*)(ws + ((size_t)7  << 20));
    bf16*  attnb   = (bf16*)(ws + ((size_t)15 << 20));
    bf16*  T1      = (bf16*)(ws + ((size_t)16 << 20));
    bf16*  kvbuf   = (bf16*)(ws + ((size_t)48 << 20));
    bf16*  hbuf    = kvbuf;
    bf16*  x2b     = (bf16*)(ws + ((size_t)176 << 20));

    const bool fat = ws_size >= ((size_t)212 << 20);

    // 0. sniff input dtype
    sniff_kernel<<<1, 256, 0, stream>>>((const unsigned int*)d_in[0], flag);

    // 1. convert params to bf16
    ConvArgs ca;
    const int   srcidx[12] = { 1, 2, 6, 7, 5, 11, 12, 9, 3, 4, 8, 10 };
    const unsigned offs[12] = { 65536, 67584, 69632, 71680, 73728, 75776, 77824, 81920,
                                1u<<20, 2621440u, 3u<<20, 5u<<20 };
    for (int i = 0; i < 12; i++) {
        ca.src[i] = d_in[srcidx[i]];
        ca.dstoff[i] = offs[i];
        ca.n[i] = in_sizes[srcidx[i]];
    }
    convert_params<<<dim3(512, 12), 256, 0, stream>>>(ca, ws, flag);

    // 2. LN1 -> T1
    ln_dyn_kernel<<<BN_/4, 256, 0, stream>>>(d_in[0], ln1_w, ln1_b, T1, flag);

    // 3. QKV GEMM: q (bf16) -> d_out, kv -> kvbuf   (Mt=128, Nt=6)
    gemm256<bf16, EPI_QKV><<<768, 512, 0, stream>>>(
        T1, qkv_w, nullptr, nullptr, flag, outb, kvbuf, BN_, 1536, 512);

    // 4. attention
    attn_logits_mfma<<<dim3(8, 64), 256, 0, stream>>>(kvbuf, partial);
    attn_softmax_kernel<<<dim3(4, 64), 256, 0, stream>>>(partial, attnb);
    attn_apply_mfma<<<dim3(16, 64), 256, 0, stream>>>(outb, attnb, T1);

    if (fat) {
        // 5. proj + bias + residual(x) -> x2b (bf16)
        gemm256<bf16, EPI_BIAS_RESID><<<256, 512, 0, stream>>>(
            T1, proj_w, proj_b, d_in[0], flag, x2b, nullptr, BN_, 512, 512);
        // 6. LN2: x2b -> T1
        ln_b16_kernel<<<BN_/4, 256, 0, stream>>>(x2b, ln2_w, ln2_b, T1);
        // 7. FC1 full: T1 -> hbuf (128MB)   (Mt=128, Nt=8)
        gemm256<bf16, EPI_BIAS_GELU><<<1024, 512, 0, stream>>>(
            T1, fc1_w, fc1_b, nullptr, flag, hbuf, nullptr, BN_, 2048, 512);
        // 8. FC2 full: hbuf -> T1 (y)       (Mt=128, Nt=2)
        gemm256<bf16, EPI_BIAS><<<256, 512, 0, stream>>>(
            hbuf, fc2_w, fc2_b, nullptr, flag, T1, nullptr, BN_, 512, 2048);
        // 9. ECA
        pooled_kernel<<<4096, 256, 0, stream>>>(T1, pooled);
        gate_kernel<<<8, 512, 0, stream>>>(pooled, eca_w, gate1);
        // 10. final: fp32 out = x2b + gate*y  (no RMW)
        final_fresh<<<dim3(64, 8, 8), 256, 0, stream>>>(T1, x2b, gate1, outf);
    } else {
        // 5. proj + bias + residual(x) -> x2 (fp32) in d_out
        gemm256<float, EPI_BIAS_RESID><<<256, 512, 0, stream>>>(
            T1, proj_w, proj_b, d_in[0], flag, outf, nullptr, BN_, 512, 512);
        // 6. LN2: d_out fp32 -> T1
        ln_f32_kernel<<<BN_/4, 256, 0, stream>>>(outf, ln2_w, ln2_b, T1);
        // 7-8. chunked FC (hbuf 64MB)
        for (int ch = 0; ch < 2; ch++) {
            bf16* Tch = T1 + (size_t)ch * 16384 * 512;
            gemm256<bf16, EPI_BIAS_GELU><<<512, 512, 0, stream>>>(
                Tch, fc1_w, fc1_b, nullptr, flag, hbuf, nullptr, 16384, 2048, 512);
            gemm256<bf16, EPI_BIAS><<<128, 512, 0, stream>>>(
                hbuf, fc2_w, fc2_b, nullptr, flag, Tch, nullptr, 16384, 512, 2048);
        }
        // 9. ECA
        pooled_kernel<<<4096, 256, 0, stream>>>(T1, pooled);
        gate_kernel<<<8, 512, 0, stream>>>(pooled, eca_w, gate1);
        // 10. final RMW on fp32 d_out
        final_rmw<<<dim3(64, 8, 8), 256, 0, stream>>>(T1, gate1, outf);
    }
}

// Round 3
// 529.903 us; speedup vs baseline: 1.1477x; 1.0376x over previous
//
#include <hip/hip_runtime.h>
#include <hip/hip_bf16.h>

typedef __bf16 bf16;
typedef __bf16 bf16x8 __attribute__((ext_vector_type(8)));
typedef float floatx4 __attribute__((ext_vector_type(4)));

#define B_    8
#define N_    4096
#define C_    512
#define BN_   32768      // B_*N_
#define HID_  2048
#define SCALE_ 0.125f    // 64^-0.5

// async 16B global -> LDS (m97 lever)
__device__ __forceinline__ void load_lds16(const void* g, void* l) {
    __builtin_amdgcn_global_load_lds(
        (const __attribute__((address_space(1))) void*)g,
        (__attribute__((address_space(3))) void*)l, 16, 0, 0);
}

// fast exact-tanh GELU: v * sigmoid(1.5957691*(v+0.044715 v^3))
// max |err| vs erf-gelu ~3e-4 < bf16 rounding of the output
__device__ __forceinline__ float gelu_fast(float v) {
    float c = fmaf(v * v, 0.044715f, 1.0f) * v;          // v + 0.044715 v^3
    float e = __builtin_amdgcn_exp2f(-2.3022082f * c);   // e^{-1.59577 c}
    return v * __builtin_amdgcn_rcpf(1.0f + e);
}

// ====================== dtype sniff ========================================
__global__ void sniff_kernel(const unsigned int* __restrict__ xw, int* __restrict__ flag)
{
    int t = threadIdx.x;
    int votes = 0;
#pragma unroll
    for (int i = 0; i < 4; i++) {
        unsigned w = xw[t * 4 + i];
        if (w == 0u) continue;
        unsigned a = w & 0xFFFFu;
        unsigned e = (a >> 7) & 0xFFu;
        if (a != 0u && e >= 110u && e <= 135u) votes++; else votes--;
    }
#pragma unroll
    for (int off = 32; off; off >>= 1) votes += __shfl_xor(votes, off);
    __shared__ int s[4];
    if ((t & 63) == 0) s[t >> 6] = votes;
    __syncthreads();
    if (t == 0) *flag = (s[0] + s[1] + s[2] + s[3]) > 0 ? 1 : 0;  // 1 = bf16
}

// ====================== param conversion ===================================
struct ConvArgs {
    const void* src[12];
    unsigned    dstoff[12];
    int         n[12];
};

__global__ __launch_bounds__(256) void convert_params(
    ConvArgs args, char* __restrict__ ws, const int* __restrict__ flag)
{
    int seg = blockIdx.y;
    int n = args.n[seg];
    int base = blockIdx.x * 2048;
    if (base >= n) return;
    bf16* dst = (bf16*)(ws + args.dstoff[seg]);
    const void* src = args.src[seg];
    bool isbf = (*flag != 0);
#pragma unroll
    for (int j = 0; j < 8; j++) {
        int idx = base + threadIdx.x + j * 256;
        if (idx < n) {
            float v = isbf ? (float)((const bf16*)src)[idx]
                           : ((const float*)src)[idx];
            dst[idx] = (bf16)v;
        }
    }
}

// ====================== LayerNorm variants =================================
__device__ __forceinline__ void ln_core(float f[8], const bf16* w, const bf16* b,
                                        int lane, bf16* outp)
{
    float s = 0.f, sq = 0.f;
#pragma unroll
    for (int j = 0; j < 8; j++) { s += f[j]; sq += f[j]*f[j]; }
#pragma unroll
    for (int off = 32; off; off >>= 1) { s += __shfl_xor(s, off); sq += __shfl_xor(sq, off); }
    float mean = s * (1.f/512.f);
    float var  = sq * (1.f/512.f) - mean*mean;
    float inv  = rsqrtf(var + 1e-5f);
    bf16x8 wv = *(const bf16x8*)(w + lane*8);
    bf16x8 bv = *(const bf16x8*)(b + lane*8);
    bf16x8 o;
#pragma unroll
    for (int j = 0; j < 8; j++) o[j] = (bf16)((f[j]-mean)*inv*(float)wv[j] + (float)bv[j]);
    *(bf16x8*)outp = o;
}

__global__ __launch_bounds__(256) void ln_dyn_kernel(
    const void* __restrict__ xv, const bf16* __restrict__ w,
    const bf16* __restrict__ b, bf16* __restrict__ out, const int* __restrict__ flag)
{
    int wave = threadIdx.x >> 6, lane = threadIdx.x & 63;
    size_t row = (size_t)blockIdx.x * 4 + wave;
    float f[8];
    if (*flag) {
        bf16x8 v = *(const bf16x8*)((const bf16*)xv + row * C_ + lane * 8);
#pragma unroll
        for (int j = 0; j < 8; j++) f[j] = (float)v[j];
    } else {
        const float4* p = (const float4*)((const float*)xv + row * C_ + lane * 8);
        float4 v0 = p[0], v1 = p[1];
        f[0]=v0.x; f[1]=v0.y; f[2]=v0.z; f[3]=v0.w;
        f[4]=v1.x; f[5]=v1.y; f[6]=v1.z; f[7]=v1.w;
    }
    ln_core(f, w, b, lane, out + row * C_ + lane*8);
}

__global__ __launch_bounds__(256) void ln_b16_kernel(
    const bf16* __restrict__ x, const bf16* __restrict__ w,
    const bf16* __restrict__ b, bf16* __restrict__ out)
{
    int wave = threadIdx.x >> 6, lane = threadIdx.x & 63;
    size_t row = (size_t)blockIdx.x * 4 + wave;
    bf16x8 v = *(const bf16x8*)(x + row * C_ + lane * 8);
    float f[8];
#pragma unroll
    for (int j = 0; j < 8; j++) f[j] = (float)v[j];
    ln_core(f, w, b, lane, out + row * C_ + lane*8);
}

__global__ __launch_bounds__(256) void ln_f32_kernel(
    const float* __restrict__ x, const bf16* __restrict__ w,
    const bf16* __restrict__ b, bf16* __restrict__ out)
{
    int wave = threadIdx.x >> 6, lane = threadIdx.x & 63;
    size_t row = (size_t)blockIdx.x * 4 + wave;
    const float4* p = (const float4*)(x + row * C_ + lane * 8);
    float4 v0 = p[0], v1 = p[1];
    float f[8] = { v0.x, v0.y, v0.z, v0.w, v1.x, v1.y, v1.z, v1.w };
    ln_core(f, w, b, lane, out + row * C_ + lane*8);
}

// ====================== 256x256 8-phase MFMA GEMM (persistent) =============
// R2 post-mortem: conflicts=0, MfmaUtil 22% — loss is 4x serialized blocks/CU
// (LDS 128K -> 1 resident) each with cold prologue + exposed epilogue and an
// 8-deep K-loop. Fix: PERSISTENT blocks (grid<=256) walking tiles id+=G, with
// CROSS-TILE PIPELINE CONTINUATION: the rolling half-tile stage map extends
// across tiles (NKT even -> slot parity continues), so tail-phase stages fill
// the NEXT tile's prologue slots, vmcnt(4) cadence never drains, and the
// epilogue overlaps the next tile's staging flight.
// Stream invariant at q3 of K-tile t (any tile): after wait vmcnt(4), all
// stages through B1(t+1) retired -> K-tile t+1 fully resident. Epilogue
// stores sit between B0(Q,0-1) stages and Q's q0 stage in vmcnt order; they
// retire during the 4 phases of Q's kt=0 (~2.5k cyc) -> minor stall only.
enum { EPI_NONE = 0, EPI_BIAS = 1, EPI_BIAS_RESID = 2, EPI_BIAS_GELU = 3, EPI_QKV = 4 };

__device__ __forceinline__ void stage_half(
    const bf16* __restrict__ G, int ldk, bf16* lbase, int t)
{
#pragma unroll
    for (int i = 0; i < 2; i++) {
        int c  = i * 512 + t;          // 16B chunk index: row = c>>3, phys slot = c&7
        int r  = c >> 3;
        int ls = (c & 7) ^ (r & 7);    // logical (global) slot for this phys slot
        load_lds16(G + (size_t)r * ldk + ls * 8, lbase + c * 8);
    }
}

// LDS reads: global (row, col8) lives at  row*64 + (col8 ^ ((row&7)<<3))
#define LOAD_AF(half)                                                          \
    _Pragma("unroll") for (int mi = 0; mi < 4; mi++) {                         \
        int row = wm * 64 + mi * 16 + l16;                                     \
        _Pragma("unroll") for (int ks = 0; ks < 2; ks++)                       \
            af[mi][ks] = *(const bf16x8*)(&Asl[s][half][0][0] + row * 64 +     \
                ((ks * 32 + quad * 8) ^ ((row & 7) << 3)));                    \
    }
#define LOAD_BF(dst, half)                                                     \
    _Pragma("unroll") for (int ni = 0; ni < 2; ni++) {                         \
        int row = wn * 32 + ni * 16 + l16;                                     \
        _Pragma("unroll") for (int ks = 0; ks < 2; ks++)                       \
            dst[ni][ks] = *(const bf16x8*)(&Bsl[s][half][0][0] + row * 64 +    \
                ((ks * 32 + quad * 8) ^ ((row & 7) << 3)));                    \
    }
#define MFMA_Q(AH, BH, BFR)                                                    \
    __builtin_amdgcn_s_barrier();                                              \
    asm volatile("s_waitcnt lgkmcnt(0)");                                      \
    __builtin_amdgcn_s_setprio(1);                                             \
    _Pragma("unroll") for (int mi = 0; mi < 4; mi++)                           \
    _Pragma("unroll") for (int ni = 0; ni < 2; ni++)                           \
    _Pragma("unroll") for (int ks = 0; ks < 2; ks++)                           \
        acc[(AH)*4+mi][(BH)*2+ni] = __builtin_amdgcn_mfma_f32_16x16x32_bf16(   \
            af[mi][ks], BFR[ni][ks], acc[(AH)*4+mi][(BH)*2+ni], 0, 0, 0);      \
    __builtin_amdgcn_s_setprio(0);                                             \
    __builtin_amdgcn_s_barrier();

template<typename OutT, int EPI>
__global__ __launch_bounds__(512, 2) void gemm256(
    const bf16* __restrict__ A, const bf16* __restrict__ W,
    const bf16* __restrict__ bias, const void* __restrict__ resid,
    const int* __restrict__ flag,
    OutT* __restrict__ Cout, bf16* __restrict__ Cout2, int M, int Nn, int K)
{
    __shared__ bf16 Asl[2][2][128][64];   // [slot][half][row][k]  64 KiB
    __shared__ bf16 Bsl[2][2][128][64];   // 64 KiB
    const int t = threadIdx.x;
    const int wv = t >> 6, lane = t & 63;
    const int quad = lane >> 4, l16 = lane & 15;
    const int wm = wv >> 2, wn = wv & 3;          // wave tile: 128 rows x 64 cols
    const int Nt = Nn >> 8;
    const int total = (M >> 8) * Nt;
    const int G = gridDim.x;
    const int NKT = K >> 6;                        // BK=64 K-tiles (NKT even)

    int id = blockIdx.x;
    if (id >= total) return;
    int m0 = (((id >> 3) / Nt) * 8 + (id & 7)) * 256;
    int n0 = ((id >> 3) % Nt) * 256;

    // ---- prologue: tile-0 K-tile 0 fully + first halves of K-tile 1 ----
    stage_half(A + (size_t)m0 * K,           K, &Asl[0][0][0][0], t);  // A0(0)
    stage_half(W + (size_t)n0 * K,           K, &Bsl[0][0][0][0], t);  // B0(0)
    stage_half(A + (size_t)(m0 + 128) * K,   K, &Asl[0][1][0][0], t);  // A1(0)
    stage_half(W + (size_t)(n0 + 128) * K,   K, &Bsl[0][1][0][0], t);  // B1(0)
    stage_half(A + (size_t)m0 * K + 64,      K, &Asl[1][0][0][0], t);  // A0(1)
    stage_half(W + (size_t)n0 * K + 64,      K, &Bsl[1][0][0][0], t);  // B0(1)
    asm volatile("s_waitcnt vmcnt(4)");
    __builtin_amdgcn_s_barrier();

    for (;;) {
        const int idn = id + G;
        const bool hn = idn < total;
        int m0n = 0, n0n = 0;
        if (hn) {
            m0n = (((idn >> 3) / Nt) * 8 + (idn & 7)) * 256;
            n0n = ((idn >> 3) % Nt) * 256;
        }

        floatx4 acc[8][4] = {};
        bf16x8 af[4][2], bf0[2][2], bf1[2][2];

        for (int kt = 0; kt < NKT; ++kt) {
            const int s = kt & 1;
            // ---- phase 0: (A0,B0) — 12 ds_reads; stage A1(next in stream)
            LOAD_AF(0)
            LOAD_BF(bf0, 0)
            {
                const bf16* p = (kt + 1 < NKT)
                    ? A + (size_t)(m0 + 128) * K + (size_t)(kt + 1) * 64
                    : (hn ? A + (size_t)(m0n + 128) * K : nullptr);
                if (p) stage_half(p, K, &Asl[s ^ 1][1][0][0], t);
            }
            MFMA_Q(0, 0, bf0)
            // ---- phase 1: (A0,B1) — 4 ds_reads; stage B1(next)
            LOAD_BF(bf1, 1)
            {
                const bf16* p = (kt + 1 < NKT)
                    ? W + (size_t)(n0 + 128) * K + (size_t)(kt + 1) * 64
                    : (hn ? W + (size_t)(n0n + 128) * K : nullptr);
                if (p) stage_half(p, K, &Bsl[s ^ 1][1][0][0], t);
            }
            MFMA_Q(0, 1, bf1)
            // ---- phase 2: (A1,B1) — 8 ds_reads; stage A0(next-next)
            LOAD_AF(1)
            {
                const bf16* p = (kt + 2 < NKT)
                    ? A + (size_t)m0 * K + (size_t)(kt + 2) * 64
                    : (hn ? A + (size_t)m0n * K + (size_t)(kt + 2 - NKT) * 64 : nullptr);
                if (p) stage_half(p, K, &Asl[s][0][0][0], t);
            }
            MFMA_Q(1, 1, bf1)
            // ---- phase 3: (A1,B0) — 0 ds_reads; stage B0(next-next); wait
            {
                const bf16* p = (kt + 2 < NKT)
                    ? W + (size_t)n0 * K + (size_t)(kt + 2) * 64
                    : (hn ? W + (size_t)n0n * K + (size_t)(kt + 2 - NKT) * 64 : nullptr);
                if (p) stage_half(p, K, &Bsl[s][0][0][0], t);
            }
            if (kt + 1 < NKT || hn) {
                if (kt + 2 < NKT || hn) asm volatile("s_waitcnt vmcnt(4)");
                else                    asm volatile("s_waitcnt vmcnt(0)");
            }
            MFMA_Q(1, 0, bf0)
        }

        // ---- epilogue (next tile's K-tile 0 already resident, 1 in flight) --
        size_t ldc = (size_t)Nn; int csub = 0; bool to2 = false;
        if (EPI == EPI_QKV) {
            if (n0 >= 512) { to2 = true; ldc = 1024; csub = 512; }
            else           { ldc = 512; }
        }
        bool isbf = false;
        if (EPI == EPI_BIAS_RESID) isbf = (*flag != 0);

#pragma unroll
        for (int mg = 0; mg < 8; mg++) {
            int rowg = m0 + (mg >> 2) * 128 + wm * 64 + (mg & 3) * 16 + quad * 4;
#pragma unroll
            for (int ng = 0; ng < 4; ng++) {
                int col = n0 + (ng >> 1) * 128 + wn * 32 + (ng & 1) * 16 + l16;
                float bv = (EPI == EPI_BIAS || EPI == EPI_BIAS_RESID || EPI == EPI_BIAS_GELU)
                           ? (float)bias[col] : 0.f;
#pragma unroll
                for (int r = 0; r < 4; r++) {
                    size_t idx = (size_t)(rowg + r) * ldc + (col - csub);
                    float v = acc[mg][ng][r] + bv;
                    if (EPI == EPI_BIAS_RESID) {
                        float rres = isbf ? (float)((const bf16*)resid)[idx]
                                          : ((const float*)resid)[idx];
                        v += rres;
                    }
                    if (EPI == EPI_BIAS_GELU)  v = gelu_fast(v);
                    if (EPI == EPI_QKV && to2) Cout2[idx] = (bf16)v;
                    else                       Cout[idx]  = (OutT)v;
                }
            }
        }

        if (!hn) break;
        id = idn; m0 = m0n; n0 = n0n;
    }
}

// ====================== attention (MFMA) ===================================
// grid (8 slices, 64 bh): partial[(bh*8+s)*4096 + d*64+e] over 512 tokens
__global__ __launch_bounds__(256) void attn_logits_mfma(
    const bf16* __restrict__ kv, float* __restrict__ partial)
{
    __shared__ bf16 Kt[64][136];
    __shared__ bf16 Vt[64][136];
    int s = blockIdx.x, bh = blockIdx.y, b = bh >> 3, h = bh & 7;
    int t = threadIdx.x, wave = t >> 6, lane = t & 63;
    int quad = lane >> 4, l16 = lane & 15;
    floatx4 acc[4] = {};
    for (int c = 0; c < 4; c++) {
        int n0 = s * 512 + c * 128;
        {
            int isv = t >> 7;
            int r   = t & 127;
            const bf16* gp = &kv[((size_t)b * N_ + n0 + r) * 1024 + h * 64 + isv * 512];
            bf16x8 rowv[8];
#pragma unroll
            for (int u = 0; u < 8; u++) rowv[u] = *(const bf16x8*)(gp + u * 8);
            bf16 (*dst)[136] = isv ? Vt : Kt;
#pragma unroll
            for (int u = 0; u < 8; u++)
#pragma unroll
                for (int jj = 0; jj < 8; jj++)
                    dst[u * 8 + jj][r] = rowv[u][jj];
        }
        __syncthreads();
#pragma unroll
        for (int ks = 0; ks < 4; ks++) {
            bf16x8 af = *(const bf16x8*)&Kt[wave * 16 + l16][ks * 32 + quad * 8];
#pragma unroll
            for (int ni = 0; ni < 4; ni++) {
                bf16x8 bfv = *(const bf16x8*)&Vt[ni * 16 + l16][ks * 32 + quad * 8];
                acc[ni] = __builtin_amdgcn_mfma_f32_16x16x32_bf16(af, bfv, acc[ni], 0, 0, 0);
            }
        }
        __syncthreads();
    }
    float* p = partial + ((size_t)bh * 8 + s) * 4096;
#pragma unroll
    for (int ni = 0; ni < 4; ni++)
#pragma unroll
        for (int r = 0; r < 4; r++)
            p[(wave * 16 + quad * 4 + r) * 64 + ni * 16 + l16] = acc[ni][r];
}

// softmax: grid (4, 64); block handles 16 d rows (wave*4 + r)
__global__ __launch_bounds__(256) void attn_softmax_kernel(
    const float* __restrict__ partial, bf16* __restrict__ attnb)
{
    int bh = blockIdx.y;
    int wave = threadIdx.x >> 6, lane = threadIdx.x & 63;
    for (int r = 0; r < 4; r++) {
        int d = blockIdx.x * 16 + wave * 4 + r;
        float v = 0.f;
#pragma unroll
        for (int s = 0; s < 8; s++) v += partial[((size_t)bh*8 + s)*4096 + d*64 + lane];
        v *= SCALE_;
        float m = v;
#pragma unroll
        for (int off = 32; off; off >>= 1) m = fmaxf(m, __shfl_xor(m, off));
        float p = expf(v - m);
        float sum = p;
#pragma unroll
        for (int off = 32; off; off >>= 1) sum += __shfl_xor(sum, off);
        attnb[(size_t)bh*4096 + d*64 + lane] = (bf16)(p / sum);
    }
}

// apply: outT[n][h*64+d] = sum_e attn[d][e] * q[n][h*64+e]
__global__ __launch_bounds__(256) void attn_apply_mfma(
    const bf16* __restrict__ q, const bf16* __restrict__ attnb,
    bf16* __restrict__ outT)
{
    int bh = blockIdx.y, b = bh >> 3, h = bh & 7;
    int t = threadIdx.x, wave = t >> 6, lane = t & 63;
    int quad = lane >> 4, l16 = lane & 15;
    int nbase = blockIdx.x * 256 + wave * 64;
    bf16x8 bfrag[4][2];
#pragma unroll
    for (int di = 0; di < 4; di++)
#pragma unroll
        for (int ks = 0; ks < 2; ks++)
            bfrag[di][ks] = *(const bf16x8*)&attnb[(size_t)bh*4096 + (di*16 + l16)*64 + ks*32 + quad*8];
    floatx4 acc[4][4] = {};
#pragma unroll
    for (int mi = 0; mi < 4; mi++) {
#pragma unroll
        for (int ks = 0; ks < 2; ks++) {
            bf16x8 af = *(const bf16x8*)&q[((size_t)b*N_ + nbase + mi*16 + l16)*512 + h*64 + ks*32 + quad*8];
#pragma unroll
            for (int di = 0; di < 4; di++)
                acc[mi][di] = __builtin_amdgcn_mfma_f32_16x16x32_bf16(af, bfrag[di][ks], acc[mi][di], 0, 0, 0);
        }
    }
#pragma unroll
    for (int mi = 0; mi < 4; mi++)
#pragma unroll
        for (int di = 0; di < 4; di++)
#pragma unroll
            for (int r = 0; r < 4; r++)
                outT[((size_t)b*N_ + nbase + mi*16 + quad*4 + r)*512 + h*64 + di*16 + l16] =
                    (bf16)acc[mi][di][r];
}

// ====================== ECA ================================================
__global__ __launch_bounds__(256) void pooled_kernel(
    const bf16* __restrict__ y, float* __restrict__ pooled)
{
    int bc = blockIdx.x;
    const bf16* p = y + (size_t)bc * 4096 + threadIdx.x * 16;
    float s = 0.f;
#pragma unroll
    for (int i = 0; i < 2; i++) {
        bf16x8 v = *(const bf16x8*)(p + i*8);
#pragma unroll
        for (int j = 0; j < 8; j++) s += (float)v[j];
    }
#pragma unroll
    for (int off = 32; off; off >>= 1) s += __shfl_xor(s, off);
    __shared__ float red[4];
    if ((threadIdx.x & 63) == 0) red[threadIdx.x >> 6] = s;
    __syncthreads();
    if (threadIdx.x == 0)
        pooled[bc] = (red[0] + red[1] + red[2] + red[3]) * (1.f/4096.f);
}

__global__ void gate_kernel(const float* __restrict__ pooled,
                            const bf16* __restrict__ eca_w, float* __restrict__ gate1)
{
    int c = threadIdx.x, b = blockIdx.x;
    float w0 = (float)eca_w[0], w1 = (float)eca_w[1], w2 = (float)eca_w[2];
    const float* p = pooled + b * 512;
    float conv = w1 * p[c];
    if (c > 0)   conv += w0 * p[c-1];
    if (c < 511) conv += w2 * p[c+1];
    float g = 1.f / (1.f + expf(-conv));
    gate1[b * 512 + c] = 1.f + g;
}

// ------- final, layout B: RMW fp32 d_out -------
__global__ __launch_bounds__(256) void final_rmw(
    const bf16* __restrict__ y, const float* __restrict__ gate1,
    float* __restrict__ out)
{
    int b = blockIdx.z, c0 = blockIdx.y * 64, n0 = blockIdx.x * 64;
    __shared__ float ytile[64][65];
    int t = threadIdx.x;
#pragma unroll
    for (int i = 0; i < 2; i++) {
        int chunk = t * 2 + i;
        int ci = chunk >> 3, nj = (chunk & 7) * 8;
        bf16x8 v = *(const bf16x8*)&y[(size_t)b * ((size_t)N_*C_) + (size_t)(c0+ci) * 4096 + n0 + nj];
#pragma unroll
        for (int j = 0; j < 8; j++) ytile[ci][nj+j] = (float)v[j];
    }
    __syncthreads();
    int cc = t & 63, nb = t >> 6;
    float g = gate1[b * 512 + c0 + cc];
    for (int p = 0; p < 16; p++) {
        int nr = p * 4 + nb;
        size_t idx = ((size_t)b * N_ + n0 + nr) * C_ + c0 + cc;
        out[idx] = out[idx] + g * ytile[cc][nr];
    }
}

// ------- final, layout A: read bf16 x2, write fresh fp32 -------
__global__ __launch_bounds__(256) void final_fresh(
    const bf16* __restrict__ y, const bf16* __restrict__ x2b,
    const float* __restrict__ gate1, float* __restrict__ out)
{
    int b = blockIdx.z, c0 = blockIdx.y * 64, n0 = blockIdx.x * 64;
    __shared__ float ytile[64][65];
    int t = threadIdx.x;
#pragma unroll
    for (int i = 0; i < 2; i++) {
        int chunk = t * 2 + i;
        int ci = chunk >> 3, nj = (chunk & 7) * 8;
        bf16x8 v = *(const bf16x8*)&y[(size_t)b * ((size_t)N_*C_) + (size_t)(c0+ci) * 4096 + n0 + nj];
#pragma unroll
        for (int j = 0; j < 8; j++) ytile[ci][nj+j] = (float)v[j];
    }
    __syncthreads();
    int cc = t & 63, nb = t >> 6;
    float g = gate1[b * 512 + c0 + cc];
    for (int p = 0; p < 16; p++) {
        int nr = p * 4 + nb;
        size_t idx = ((size_t)b * N_ + n0 + nr) * C_ + c0 + cc;
        out[idx] = (float)x2b[idx] + g * ytile[cc][nr];
    }
}

// ====================== launcher ===========================================
// Common (both layouts):
//   0: flag | 4K: pooled | 20K: gate1 | 64K-84K: small params bf16
//   1M: qkv_w | 2.5M: proj_w | 3M: fc1_w | 5M: fc2_w
//   7M-15M: partial fp32 (8 slices) | 15M-15.5M: attnb bf16
//   16M-48M: T1 | 48M: kvbuf (64MB)
// Layout A (ws >= 212MB): hbuf 48-176M (full h), x2b bf16 176-210M,
//   proj->x2b, ln_b16, unchunked FC, final_fresh.
// Layout B: hbuf=kvbuf 48-112M, x2 fp32 in d_out, chunked FC, final_rmw.
extern "C" void kernel_launch(void* const* d_in, const int* in_sizes, int n_in,
                              void* d_out, int out_size, void* d_ws, size_t ws_size,
                              hipStream_t stream)
{
    float* outf = (float*)d_out;
    bf16*  outb = (bf16*)d_out;
    char* ws = (char*)d_ws;

    int*   flag    = (int*)ws;
    float* pooled  = (float*)(ws + 4096);
    float* gate1   = (float*)(ws + 20480);
    bf16* ln1_w = (bf16*)(ws + 65536);
    bf16* ln1_b = (bf16*)(ws + 67584);
    bf16* ln2_w = (bf16*)(ws + 69632);
    bf16* ln2_b = (bf16*)(ws + 71680);
    bf16* proj_b= (bf16*)(ws + 73728);
    bf16* fc2_b = (bf16*)(ws + 75776);
    bf16* eca_w = (bf16*)(ws + 77824);
    bf16* fc1_b = (bf16*)(ws + 81920);
    bf16* qkv_w = (bf16*)(ws + ((size_t)1 << 20));
    bf16* proj_w= (bf16*)(ws + (size_t)2621440);
    bf16* fc1_w = (bf16*)(ws + ((size_t)3 << 20));
    bf16* fc2_w = (bf16*)(ws + ((size_t)5 << 20));
    float* partial = (float*)(ws + ((size_t)7  << 20));
    bf16*  attnb   = (bf16*)(ws + ((size_t)15 << 20));
    bf16*  T1      = (bf16*)(ws + ((size_t)16 << 20));
    bf16*  kvbuf   = (bf16*)(ws + ((size_t)48 << 20));
    bf16*  hbuf    = kvbuf;
    bf16*  x2b     = (bf16*)(ws + ((size_t)176 << 20));

    const bool fat = ws_size >= ((size_t)212 << 20);

    // 0. sniff input dtype
    sniff_kernel<<<1, 256, 0, stream>>>((const unsigned int*)d_in[0], flag);

    // 1. convert params to bf16
    ConvArgs ca;
    const int   srcidx[12] = { 1, 2, 6, 7, 5, 11, 12, 9, 3, 4, 8, 10 };
    const unsigned offs[12] = { 65536, 67584, 69632, 71680, 73728, 75776, 77824, 81920,
                                1u<<20, 2621440u, 3u<<20, 5u<<20 };
    for (int i = 0; i < 12; i++) {
        ca.src[i] = d_in[srcidx[i]];
        ca.dstoff[i] = offs[i];
        ca.n[i] = in_sizes[srcidx[i]];
    }
    convert_params<<<dim3(512, 12), 256, 0, stream>>>(ca, ws, flag);

    // 2. LN1 -> T1
    ln_dyn_kernel<<<BN_/4, 256, 0, stream>>>(d_in[0], ln1_w, ln1_b, T1, flag);

    // 3. QKV GEMM: q (bf16) -> d_out, kv -> kvbuf  (768 tiles, 3/block)
    gemm256<bf16, EPI_QKV><<<256, 512, 0, stream>>>(
        T1, qkv_w, nullptr, nullptr, flag, outb, kvbuf, BN_, 1536, 512);

    // 4. attention
    attn_logits_mfma<<<dim3(8, 64), 256, 0, stream>>>(kvbuf, partial);
    attn_softmax_kernel<<<dim3(4, 64), 256, 0, stream>>>(partial, attnb);
    attn_apply_mfma<<<dim3(16, 64), 256, 0, stream>>>(outb, attnb, T1);

    if (fat) {
        // 5. proj + bias + residual(x) -> x2b (bf16)   (256 tiles, 1/block)
        gemm256<bf16, EPI_BIAS_RESID><<<256, 512, 0, stream>>>(
            T1, proj_w, proj_b, d_in[0], flag, x2b, nullptr, BN_, 512, 512);
        // 6. LN2: x2b -> T1
        ln_b16_kernel<<<BN_/4, 256, 0, stream>>>(x2b, ln2_w, ln2_b, T1);
        // 7. FC1 full: T1 -> hbuf (128MB)  (1024 tiles, 4/block)
        gemm256<bf16, EPI_BIAS_GELU><<<256, 512, 0, stream>>>(
            T1, fc1_w, fc1_b, nullptr, flag, hbuf, nullptr, BN_, 2048, 512);
        // 8. FC2 full: hbuf -> T1 (y)      (256 tiles, 1/block)
        gemm256<bf16, EPI_BIAS><<<256, 512, 0, stream>>>(
            hbuf, fc2_w, fc2_b, nullptr, flag, T1, nullptr, BN_, 512, 2048);
        // 9. ECA
        pooled_kernel<<<4096, 256, 0, stream>>>(T1, pooled);
        gate_kernel<<<8, 512, 0, stream>>>(pooled, eca_w, gate1);
        // 10. final: fp32 out = x2b + gate*y  (no RMW)
        final_fresh<<<dim3(64, 8, 8), 256, 0, stream>>>(T1, x2b, gate1, outf);
    } else {
        // 5. proj + bias + residual(x) -> x2 (fp32) in d_out
        gemm256<float, EPI_BIAS_RESID><<<256, 512, 0, stream>>>(
            T1, proj_w, proj_b, d_in[0], flag, outf, nullptr, BN_, 512, 512);
        // 6. LN2: d_out fp32 -> T1
        ln_f32_kernel<<<BN_/4, 256, 0, stream>>>(outf, ln2_w, ln2_b, T1);
        // 7-8. chunked FC (hbuf 64MB)
        for (int ch = 0; ch < 2; ch++) {
            bf16* Tch = T1 + (size_t)ch * 16384 * 512;
            gemm256<bf16, EPI_BIAS_GELU><<<256, 512, 0, stream>>>(
                Tch, fc1_w, fc1_b, nullptr, flag, hbuf, nullptr, 16384, 2048, 512);
            gemm256<bf16, EPI_BIAS><<<128, 512, 0, stream>>>(
                hbuf, fc2_w, fc2_b, nullptr, flag, Tch, nullptr, 16384, 512, 2048);
        }
        // 9. ECA
        pooled_kernel<<<4096, 256, 0, stream>>>(T1, pooled);
        gate_kernel<<<8, 512, 0, stream>>>(pooled, eca_w, gate1);
        // 10. final RMW on fp32 d_out
        final_rmw<<<dim3(64, 8, 8), 256, 0, stream>>>(T1, gate1, outf);
    }
}